// Round 6
// baseline (436.609 us; speedup 1.0000x reference)
//
#include <hip/hip_runtime.h>

// Block: LN1 -> per-head QKV -> causal attn -> proj+resid -> LN2 -> FF(relu)+resid
// B=4, T=2048, C=1024, H=16, HD=64.  All GEMMs bf16 MFMA (16x16x32), fp32 accum.

#define B_ 4
#define T_ 2048
#define C_ 1024
#define H_ 16
#define BT_ 8192

typedef __attribute__((ext_vector_type(8))) __bf16 bf16x8;
typedef __attribute__((ext_vector_type(4))) __bf16 bf16x4;
typedef __attribute__((ext_vector_type(4))) float f32x4;

#define WAIT_LGKM0 asm volatile("s_waitcnt lgkmcnt(0)" ::: "memory")
#define WAIT_VM(N) asm volatile("s_waitcnt vmcnt(" #N ")" ::: "memory")
#define NOSTG ((void)0)

__device__ __forceinline__ void gload_lds16(const void* g, void* l) {
  __builtin_amdgcn_global_load_lds((const __attribute__((address_space(1))) void*)g,
                                   (__attribute__((address_space(3))) void*)l, 16, 0, 0);
}

__device__ __forceinline__ void block_sync() {
  asm volatile("" ::: "memory");
  __builtin_amdgcn_s_barrier();
  asm volatile("" ::: "memory");
}

// ---------------- transpose fp32 [R][Cc] -> bf16 [Cc][R], batched ----------------
__global__ __launch_bounds__(256) void transpose_f32_bf16(
    const float* __restrict__ in, __bf16* __restrict__ out,
    int R, int Cc, long inBatch, long outBatch) {
  __shared__ float tile[32][33];
  const int tx = threadIdx.x, ty = threadIdx.y;
  in += (long)blockIdx.z * inBatch;
  out += (long)blockIdx.z * outBatch;
  const int r0 = blockIdx.y * 32, c0 = blockIdx.x * 32;
#pragma unroll
  for (int i = 0; i < 4; i++)
    tile[ty + i * 8][tx] = in[(long)(r0 + ty + i * 8) * Cc + c0 + tx];
  __syncthreads();
#pragma unroll
  for (int i = 0; i < 4; i++)
    out[(long)(c0 + ty + i * 8) * R + r0 + tx] = (__bf16)tile[tx][ty + i * 8];
}

// ---------------- LayerNorm: fp32 [rows][1024] -> bf16 ----------------
__global__ __launch_bounds__(256) void ln_fwd(const float* __restrict__ x,
                                              const float* __restrict__ g,
                                              const float* __restrict__ bta,
                                              __bf16* __restrict__ out) {
  const long row = blockIdx.x;
  const int tid = threadIdx.x;
  float4 v = ((const float4*)(x + row * C_))[tid];
  float vals[4] = {v.x, v.y, v.z, v.w};
  float s = vals[0] + vals[1] + vals[2] + vals[3];
  float s2 = vals[0] * vals[0] + vals[1] * vals[1] + vals[2] * vals[2] + vals[3] * vals[3];
#pragma unroll
  for (int o = 1; o < 64; o <<= 1) {
    s += __shfl_xor(s, o);
    s2 += __shfl_xor(s2, o);
  }
  __shared__ float red[8];
  const int lane = tid & 63, wid = tid >> 6;
  if (lane == 0) { red[wid] = s; red[wid + 4] = s2; }
  __syncthreads();
  const float S = red[0] + red[1] + red[2] + red[3];
  const float S2 = red[4] + red[5] + red[6] + red[7];
  const float mu = S * (1.0f / C_);
  const float var = S2 * (1.0f / C_) - mu * mu;
  const float rs = rsqrtf(var + 1e-5f);
  bf16x4 o4;
#pragma unroll
  for (int j = 0; j < 4; j++) {
    const int c = tid * 4 + j;
    o4[j] = (__bf16)((vals[j] - mu) * rs * g[c] + bta[c]);
  }
  *(bf16x4*)(out + row * C_ + tid * 4) = o4;
}

// ---------------- GEMM 256x256, per-wave 128x64, 4-phase/K-tile, counted vmcnt ----------------
// A[M,K] x Bt[N,K]. 512 thr = 8 waves (2M x 4N), per-wave 128x64 = 8rf x 4cf.
// K-tile 64 = 2 K-halves of 32. LDS 128KB: A[2buf][2kh][256x32] + B[2buf][2kh][256x32].
// Per phase: {4-8 ds_read_b128 | 2 gload_lds | (vmcnt(8) at ph1/ph3) | barrier |
//             lgkmcnt(0)+sched_barrier | setprio(1) 16 MFMA setprio(0) | barrier}.
// B-frags read once per K-half, reused across both rf-halves -> 6 reads/16 MFMA avg.
// vmcnt(8) = 2 half-tiles (4 loads each) in flight; never drained to 0 mid-loop.
// Swizzle: 16B-chunk pos ^= ((row>>1)&3) on stage-source and ds_read (0 conflicts).
// EPI 0: bf16 bias+relu. 1: QKV route (V transposed). 2: fp32 bias+resid. 3: fp32 atomicAdd (+bias if k0==0).
template <int EPI, int SPLITK>
__global__ __launch_bounds__(512, 2) void gemm2x(
    const __bf16* __restrict__ A, const __bf16* __restrict__ Bt,
    void* out0, void* out1, void* out2,
    const float* __restrict__ bias, const float* __restrict__ resid,
    int M, int N, int K, int nwg) {
  __shared__ __bf16 sm[65536];   // 128 KB
  __bf16* ldsA = &sm[0];         // 4 slots x 8192 el (buf*2+kh)
  __bf16* ldsB = &sm[32768];
  const int tid = threadIdx.x, lane = tid & 63, wid = tid >> 6;
  const int wm = wid >> 2, wn = wid & 3;
  const int l15 = lane & 15, qtr = lane >> 4;
  // bijective chunked XCD swizzle (nwg % 8 == 0)
  const int q8 = nwg >> 3;
  int wg = (blockIdx.x & 7) * q8 + (blockIdx.x >> 3);
  int k0 = 0, KS = K;
  if (SPLITK) { KS = K >> 1; k0 = (wg >> 7) * KS; wg &= 127; }
  const int mBlocks = M >> 8;
  const long mBase = (long)(wg % mBlocks) * 256;
  const long nBase = (long)(wg / mBlocks) * 256;
  const int NT = KS >> 6;

  f32x4 acc[8][4] = {};
  bf16x8 bfr[4];

  const int posRd = (qtr ^ ((l15 >> 1) & 3)) * 8;
  const int aRdB = (wm * 128 + l15) * 32 + posRd;
  const int bRdB = (wn * 64 + l15) * 32 + posRd;

  const int spos = (tid & 3) ^ ((tid >> 3) & 3);
  const __bf16* aS0 = A + (mBase + (tid >> 2)) * (long)K + k0 + spos * 8;
  const __bf16* aS1 = aS0 + 128 * (long)K;
  const __bf16* bS0 = Bt + (nBase + (tid >> 2)) * (long)K + k0 + spos * 8;
  const __bf16* bS1 = bS0 + 128 * (long)K;

#define STGA(BUF, KH, KT)                                                                     \
  do {                                                                                        \
    gload_lds16(aS0 + (KT) * 64 + (KH) * 32, ldsA + ((BUF) * 2 + (KH)) * 8192 + tid * 8);     \
    gload_lds16(aS1 + (KT) * 64 + (KH) * 32, ldsA + ((BUF) * 2 + (KH)) * 8192 + 4096 + tid * 8); \
  } while (0)
#define STGB(BUF, KH, KT)                                                                     \
  do {                                                                                        \
    gload_lds16(bS0 + (KT) * 64 + (KH) * 32, ldsB + ((BUF) * 2 + (KH)) * 8192 + tid * 8);     \
    gload_lds16(bS1 + (KT) * 64 + (KH) * 32, ldsB + ((BUF) * 2 + (KH)) * 8192 + 4096 + tid * 8); \
  } while (0)

#define PH(BUF, KH, RFH, WAITOP, STG)                                                        \
  do {                                                                                       \
    const __bf16* sA_ = ldsA + ((BUF) * 2 + (KH)) * 8192;                                    \
    const __bf16* sB_ = ldsB + ((BUF) * 2 + (KH)) * 8192;                                    \
    bf16x8 af0 = *(const bf16x8*)&sA_[aRdB + (RFH) * 2048];                                  \
    bf16x8 af1 = *(const bf16x8*)&sA_[aRdB + (RFH) * 2048 + 512];                            \
    bf16x8 af2 = *(const bf16x8*)&sA_[aRdB + (RFH) * 2048 + 1024];                           \
    bf16x8 af3 = *(const bf16x8*)&sA_[aRdB + (RFH) * 2048 + 1536];                           \
    if ((RFH) == 0) {                                                                        \
      bfr[0] = *(const bf16x8*)&sB_[bRdB];                                                   \
      bfr[1] = *(const bf16x8*)&sB_[bRdB + 512];                                             \
      bfr[2] = *(const bf16x8*)&sB_[bRdB + 1024];                                            \
      bfr[3] = *(const bf16x8*)&sB_[bRdB + 1536];                                            \
    }                                                                                        \
    STG;                                                                                     \
    WAITOP;                                                                                  \
    block_sync();                                                                            \
    WAIT_LGKM0;                                                                              \
    __builtin_amdgcn_sched_barrier(0);                                                       \
    __builtin_amdgcn_s_setprio(1);                                                           \
    acc[(RFH)*4+0][0] = __builtin_amdgcn_mfma_f32_16x16x32_bf16(af0, bfr[0], acc[(RFH)*4+0][0], 0, 0, 0); \
    acc[(RFH)*4+0][1] = __builtin_amdgcn_mfma_f32_16x16x32_bf16(af0, bfr[1], acc[(RFH)*4+0][1], 0, 0, 0); \
    acc[(RFH)*4+0][2] = __builtin_amdgcn_mfma_f32_16x16x32_bf16(af0, bfr[2], acc[(RFH)*4+0][2], 0, 0, 0); \
    acc[(RFH)*4+0][3] = __builtin_amdgcn_mfma_f32_16x16x32_bf16(af0, bfr[3], acc[(RFH)*4+0][3], 0, 0, 0); \
    acc[(RFH)*4+1][0] = __builtin_amdgcn_mfma_f32_16x16x32_bf16(af1, bfr[0], acc[(RFH)*4+1][0], 0, 0, 0); \
    acc[(RFH)*4+1][1] = __builtin_amdgcn_mfma_f32_16x16x32_bf16(af1, bfr[1], acc[(RFH)*4+1][1], 0, 0, 0); \
    acc[(RFH)*4+1][2] = __builtin_amdgcn_mfma_f32_16x16x32_bf16(af1, bfr[2], acc[(RFH)*4+1][2], 0, 0, 0); \
    acc[(RFH)*4+1][3] = __builtin_amdgcn_mfma_f32_16x16x32_bf16(af1, bfr[3], acc[(RFH)*4+1][3], 0, 0, 0); \
    acc[(RFH)*4+2][0] = __builtin_amdgcn_mfma_f32_16x16x32_bf16(af2, bfr[0], acc[(RFH)*4+2][0], 0, 0, 0); \
    acc[(RFH)*4+2][1] = __builtin_amdgcn_mfma_f32_16x16x32_bf16(af2, bfr[1], acc[(RFH)*4+2][1], 0, 0, 0); \
    acc[(RFH)*4+2][2] = __builtin_amdgcn_mfma_f32_16x16x32_bf16(af2, bfr[2], acc[(RFH)*4+2][2], 0, 0, 0); \
    acc[(RFH)*4+2][3] = __builtin_amdgcn_mfma_f32_16x16x32_bf16(af2, bfr[3], acc[(RFH)*4+2][3], 0, 0, 0); \
    acc[(RFH)*4+3][0] = __builtin_amdgcn_mfma_f32_16x16x32_bf16(af3, bfr[0], acc[(RFH)*4+3][0], 0, 0, 0); \
    acc[(RFH)*4+3][1] = __builtin_amdgcn_mfma_f32_16x16x32_bf16(af3, bfr[1], acc[(RFH)*4+3][1], 0, 0, 0); \
    acc[(RFH)*4+3][2] = __builtin_amdgcn_mfma_f32_16x16x32_bf16(af3, bfr[2], acc[(RFH)*4+3][2], 0, 0, 0); \
    acc[(RFH)*4+3][3] = __builtin_amdgcn_mfma_f32_16x16x32_bf16(af3, bfr[3], acc[(RFH)*4+3][3], 0, 0, 0); \
    __builtin_amdgcn_s_setprio(0);                                                           \
    block_sync();                                                                            \
  } while (0)

  // prologue: stage h0=(0,kh0), h1=(0,kh1), h2=(1,kh0); wait h0
  STGA(0, 0, 0); STGB(0, 0, 0);
  STGA(0, 1, 0); STGB(0, 1, 0);
  STGA(1, 0, 1); STGB(1, 0, 1);
  WAIT_VM(8);
  block_sync();

  int b = 0;
  for (int t = 0; t + 2 < NT; ++t) {
    PH(b, 0, 0, NOSTG, STGA(b ^ 1, 1, t + 1));
    PH(b, 0, 1, WAIT_VM(8), STGB(b ^ 1, 1, t + 1));
    PH(b, 1, 0, NOSTG, STGA(b, 0, t + 2));
    PH(b, 1, 1, WAIT_VM(8), STGB(b, 0, t + 2));
    b ^= 1;
  }
  // tile NT-2 (b==0, NT even): stage last half (NT-1, kh1)
  PH(0, 0, 0, NOSTG, STGA(1, 1, NT - 1));
  PH(0, 0, 1, WAIT_VM(8), STGB(1, 1, NT - 1));
  PH(0, 1, 0, NOSTG, NOSTG);
  PH(0, 1, 1, WAIT_VM(4), NOSTG);
  // tile NT-1 (b==1): no staging
  PH(1, 0, 0, NOSTG, NOSTG);
  PH(1, 0, 1, WAIT_VM(0), NOSTG);
  PH(1, 1, 0, NOSTG, NOSTG);
  PH(1, 1, 1, WAIT_VM(0), NOSTG);

#undef PH
#undef STGA
#undef STGB

  // ---- epilogue
  if (EPI == 0) {
    __bf16* outB = (__bf16*)out0;
#pragma unroll
    for (int cf = 0; cf < 4; cf++) {
      const long gc = nBase + wn * 64 + cf * 16 + l15;
      const float bv = bias[gc];
#pragma unroll
      for (int rf = 0; rf < 8; rf++) {
        const long gr0 = mBase + wm * 128 + rf * 16 + qtr * 4;
#pragma unroll
        for (int r = 0; r < 4; r++)
          outB[(gr0 + r) * (long)N + gc] = (__bf16)fmaxf(acc[rf][cf][r] + bv, 0.0f);
      }
    }
  } else if (EPI == 2) {
    float* outF = (float*)out0;
#pragma unroll
    for (int cf = 0; cf < 4; cf++) {
      const long gc = nBase + wn * 64 + cf * 16 + l15;
      const float bv = bias[gc];
#pragma unroll
      for (int rf = 0; rf < 8; rf++) {
        const long gr0 = mBase + wm * 128 + rf * 16 + qtr * 4;
#pragma unroll
        for (int r = 0; r < 4; r++)
          outF[(gr0 + r) * (long)N + gc] = acc[rf][cf][r] + bv + resid[(gr0 + r) * (long)N + gc];
      }
    }
  } else if (EPI == 3) {
    float* outF = (float*)out0;
#pragma unroll
    for (int cf = 0; cf < 4; cf++) {
      const long gc = nBase + wn * 64 + cf * 16 + l15;
      const float bv = (k0 == 0) ? bias[gc] : 0.0f;
#pragma unroll
      for (int rf = 0; rf < 8; rf++) {
        const long gr0 = mBase + wm * 128 + rf * 16 + qtr * 4;
#pragma unroll
        for (int r = 0; r < 4; r++)
          atomicAdd(&outF[(gr0 + r) * (long)N + gc], acc[rf][cf][r] + bv);
      }
    }
  } else {
    // QKV routing: seg 0 -> Q [BT,1024], 1 -> K [BT,1024], 2 -> V transposed [1024][BT]
    const int seg = (int)(nBase >> 10);
#pragma unroll
    for (int cf = 0; cf < 4; cf++) {
      const long gc = nBase + wn * 64 + cf * 16 + l15;
      const long cc = gc & 1023;
#pragma unroll
      for (int rf = 0; rf < 8; rf++) {
        const long gr0 = mBase + wm * 128 + rf * 16 + qtr * 4;
        if (seg == 0) {
          __bf16* Qb = (__bf16*)out0;
#pragma unroll
          for (int r = 0; r < 4; r++) Qb[(gr0 + r) * 1024 + cc] = (__bf16)acc[rf][cf][r];
        } else if (seg == 1) {
          __bf16* Kb = (__bf16*)out1;
#pragma unroll
          for (int r = 0; r < 4; r++) Kb[(gr0 + r) * 1024 + cc] = (__bf16)acc[rf][cf][r];
        } else {
          __bf16* Vtg = (__bf16*)out2;
          bf16x4 v4;
#pragma unroll
          for (int r = 0; r < 4; r++) v4[r] = (__bf16)acc[rf][cf][r];
          *(bf16x4*)&Vtg[cc * (long)BT_ + gr0] = v4;
        }
      }
    }
  }
}

// ---------------- causal flash attention v2 ----------------
// grid (B*H, 16): blockIdx.x = bh so all q-blocks of a head share an XCD (wgid%8).
// log2-domain softmax (Q pre-scaled by 0.125*log2e); defer-max (T13, THR=8).
#define PSTR 72
__global__ __launch_bounds__(512, 6) void attn_fwd2(
    const __bf16* __restrict__ Qg, const __bf16* __restrict__ Kg,
    const __bf16* __restrict__ Vtg, __bf16* __restrict__ O) {
  __shared__ __bf16 Ks[2][64 * 64];
  __shared__ __bf16 Vs[2][64 * 64];
  __shared__ __bf16 Ps[128 * PSTR];
  const int tid = threadIdx.x, lane = tid & 63, wid = tid >> 6;
  const int bh = blockIdx.x, b = bh >> 4, h = bh & 15;
  const int qx = 15 - blockIdx.y;           // heavy blocks first
  const int qBase = qx * 128;
  const int qw = qBase + wid * 16;
  const int qwTop = qw + 15;
  const long bT = (long)b * T_;
  const int l15 = lane & 15, qtr = lane >> 4;
  const int q_lane = qw + l15;

  const int srow = tid >> 3;
  const int schunk = (tid & 7) ^ (srow & 7);
  const __bf16* kSrcBase = Kg + (bT + srow) * C_ + h * 64 + schunk * 8;
  const __bf16* vSrcBase = Vtg + (long)(h * 64 + srow) * BT_ + bT + schunk * 8;
  __bf16* kDst = &Ks[0][tid * 8];
  __bf16* vDst = &Vs[0][tid * 8];
  const int bufStride = 64 * 64;

  bf16x8 q0s, q1s;
  {
    const float SC = 0.125f * 1.44269504089f;  // 1/sqrt(64) * log2(e)
    bf16x8 r0 = *(const bf16x8*)(Qg + (bT + q_lane) * C_ + h * 64 + qtr * 8);
    bf16x8 r1 = *(const bf16x8*)(Qg + (bT + q_lane) * C_ + h * 64 + 32 + qtr * 8);
#pragma unroll
    for (int j = 0; j < 8; j++) {
      q0s[j] = (__bf16)((float)r0[j] * SC);
      q1s[j] = (__bf16)((float)r1[j] * SC);
    }
  }

  f32x4 o[4] = {};
  float m_ = -1e30f, l_ = 0.0f;
  const int nkt = 2 * qx + 2;

  gload_lds16(kSrcBase, kDst);
  gload_lds16(vSrcBase, vDst);
  __syncthreads();

  int buf = 0;
  for (int t = 0; t < nkt; t++) {
    const int k0 = t * 64;
    if (t + 1 < nkt) {
      const long koff = (long)(k0 + 64);
      gload_lds16(kSrcBase + koff * C_, kDst + (buf ^ 1) * bufStride);
      gload_lds16(vSrcBase + koff, vDst + (buf ^ 1) * bufStride);
    }
    if (k0 <= qwTop) {
      const __bf16* ks = Ks[buf];
      const __bf16* vs = Vs[buf];
      f32x4 sT[4] = {};
      __builtin_amdgcn_s_setprio(1);
#pragma unroll
      for (int kb = 0; kb < 4; kb++) {
        bf16x8 aK0 = *(const bf16x8*)&ks[(kb * 16 + l15) * 64 + ((qtr ^ (l15 & 7)) * 8)];
        bf16x8 aK1 = *(const bf16x8*)&ks[(kb * 16 + l15) * 64 + (((4 + qtr) ^ (l15 & 7)) * 8)];
        sT[kb] = __builtin_amdgcn_mfma_f32_16x16x32_bf16(aK0, q0s, sT[kb], 0, 0, 0);
        sT[kb] = __builtin_amdgcn_mfma_f32_16x16x32_bf16(aK1, q1s, sT[kb], 0, 0, 0);
      }
      __builtin_amdgcn_s_setprio(0);
      if (k0 + 63 > qw) {
#pragma unroll
        for (int kb = 0; kb < 4; kb++)
#pragma unroll
          for (int r = 0; r < 4; r++)
            if (k0 + kb * 16 + qtr * 4 + r > q_lane) sT[kb][r] = -1e30f;
      }
      float mx = -1e30f;
#pragma unroll
      for (int kb = 0; kb < 4; kb++)
#pragma unroll
        for (int r = 0; r < 4; r++) mx = fmaxf(mx, sT[kb][r]);
      mx = fmaxf(mx, __shfl_xor(mx, 16));
      mx = fmaxf(mx, __shfl_xor(mx, 32));
      // defer-max: skip rescale when no row grew by > 8 (log2 units; P <= 256)
      const bool defer = __all(mx - m_ <= 8.0f);
      const float mnew = defer ? m_ : fmaxf(m_, mx);
      float psum = 0.0f;
#pragma unroll
      for (int kb = 0; kb < 4; kb++)
#pragma unroll
        for (int r = 0; r < 4; r++) {
          const float pv = exp2f(sT[kb][r] - mnew);
          psum += pv;
          Ps[(wid * 16 + l15) * PSTR + kb * 16 + qtr * 4 + r] = (__bf16)pv;
        }
      psum += __shfl_xor(psum, 16);
      psum += __shfl_xor(psum, 32);
      if (defer) {
        l_ += psum;
      } else {
        const float fac = exp2f(m_ - mnew);
        l_ = l_ * fac + psum;
        m_ = mnew;
#pragma unroll
        for (int r = 0; r < 4; r++) {
          const float fr = __shfl(fac, (lane & 48) + qtr * 4 + r);
#pragma unroll
          for (int dg = 0; dg < 4; dg++) o[dg][r] *= fr;
        }
      }
      __builtin_amdgcn_s_setprio(1);
#pragma unroll
      for (int s = 0; s < 2; s++) {
        bf16x8 aP = *(const bf16x8*)&Ps[(wid * 16 + l15) * PSTR + s * 32 + qtr * 8];
#pragma unroll
        for (int dg = 0; dg < 4; dg++) {
          bf16x8 bV = *(const bf16x8*)&vs[(dg * 16 + l15) * 64 + (((s * 4 + qtr) ^ (l15 & 7)) * 8)];
          o[dg] = __builtin_amdgcn_mfma_f32_16x16x32_bf16(aP, bV, o[dg], 0, 0, 0);
        }
      }
      __builtin_amdgcn_s_setprio(0);
    }
    __syncthreads();
    buf ^= 1;
  }

  const float linv = 1.0f / l_;
#pragma unroll
  for (int r = 0; r < 4; r++) {
    const float lr = __shfl(linv, (lane & 48) + qtr * 4 + r);
    const long row = bT + qw + qtr * 4 + r;
#pragma unroll
    for (int dg = 0; dg < 4; dg++)
      O[row * C_ + h * 64 + dg * 16 + l15] = (__bf16)(o[dg][r] * lr);
  }
}

// ---------------- launch ----------------
extern "C" void kernel_launch(void* const* d_in, const int* in_sizes, int n_in,
                              void* d_out, int out_size, void* d_ws, size_t ws_size,
                              hipStream_t stream) {
  const float* x = (const float*)d_in[0];
  const float* wq = (const float*)d_in[1];
  const float* wk = (const float*)d_in[2];
  const float* wv = (const float*)d_in[3];
  const float* wproj = (const float*)d_in[4];
  const float* bproj = (const float*)d_in[5];
  const float* w1 = (const float*)d_in[6];
  const float* b1 = (const float*)d_in[7];
  const float* w2 = (const float*)d_in[8];
  const float* b2 = (const float*)d_in[9];
  const float* g1 = (const float*)d_in[10];
  const float* be1 = (const float*)d_in[11];
  const float* g2 = (const float*)d_in[12];
  const float* be2 = (const float*)d_in[13];

  char* ws = (char*)d_ws;
  const size_t MB = 1024ull * 1024ull;
  __bf16* h1 = (__bf16*)(ws + 0);          // 16MB; reused as att after QKV
  __bf16* Qb = (__bf16*)(ws + 16 * MB);    // 16MB; reused as h2 after attn
  __bf16* Kb = (__bf16*)(ws + 32 * MB);    // 16MB
  __bf16* Vtg = (__bf16*)(ws + 48 * MB);   // 16MB, V pre-transposed [C][B*T]
  __bf16* ff1 = (__bf16*)(ws + 32 * MB);   // 64MB, aliases Kb/Vtg (dead after attn)
  __bf16* wqt = (__bf16*)(ws + 96 * MB);   // wqt/wkt/wvt contiguous => [3072][1024]
  __bf16* wkt = (__bf16*)(ws + 98 * MB);
  __bf16* wvt = (__bf16*)(ws + 100 * MB);
  __bf16* wpt = (__bf16*)(ws + 102 * MB);
  __bf16* w1t = (__bf16*)(ws + 104 * MB);  // 8MB
  __bf16* w2t = (__bf16*)(ws + 112 * MB);  // 8MB
  __bf16* att = h1;
  __bf16* h2 = Qb;
  float* xout = (float*)d_out;

  dim3 tb(32, 8);
  transpose_f32_bf16<<<dim3(2, 32, 16), tb, 0, stream>>>(wq, wqt, 1024, 64, 1024 * 64, 64 * 1024);
  transpose_f32_bf16<<<dim3(2, 32, 16), tb, 0, stream>>>(wk, wkt, 1024, 64, 1024 * 64, 64 * 1024);
  transpose_f32_bf16<<<dim3(2, 32, 16), tb, 0, stream>>>(wv, wvt, 1024, 64, 1024 * 64, 64 * 1024);
  transpose_f32_bf16<<<dim3(32, 32, 1), tb, 0, stream>>>(wproj, wpt, 1024, 1024, 0, 0);
  transpose_f32_bf16<<<dim3(128, 32, 1), tb, 0, stream>>>(w1, w1t, 1024, 4096, 0, 0);
  transpose_f32_bf16<<<dim3(32, 128, 1), tb, 0, stream>>>(w2, w2t, 4096, 1024, 0, 0);

  ln_fwd<<<8192, 256, 0, stream>>>(x, g1, be1, h1);
  // fused QKV: Bt = [wqt|wkt|wvt] = [3072][1024]; 32 m x 12 n = 384 blocks
  gemm2x<1, 0><<<384, 512, 0, stream>>>(h1, wqt, Qb, Kb, Vtg, nullptr, nullptr, 8192, 3072, 1024, 384);
  attn_fwd2<<<dim3(64, 16), 512, 0, stream>>>(Qb, Kb, Vtg, att);
  gemm2x<2, 0><<<128, 512, 0, stream>>>(att, wpt, xout, nullptr, nullptr, bproj, x, 8192, 1024, 1024, 128);
  ln_fwd<<<8192, 256, 0, stream>>>(xout, g2, be2, h2);
  gemm2x<0, 0><<<512, 512, 0, stream>>>(h2, w1t, ff1, nullptr, nullptr, b1, nullptr, 8192, 4096, 1024, 512);
  // FF2 split-K=2: 256 blocks, halves atomically accumulate into xout (bias on half 0)
  gemm2x<3, 1><<<256, 512, 0, stream>>>(ff1, w2t, xout, nullptr, nullptr, b2, nullptr, 8192, 1024, 4096, 256);
}

// Round 7
// 385.826 us; speedup vs baseline: 1.1316x; 1.1316x over previous
//
#include <hip/hip_runtime.h>

// Block: LN1 -> per-head QKV -> causal attn -> proj+resid -> LN2 -> FF(relu)+resid
// B=4, T=2048, C=1024, H=16, HD=64.  All GEMMs bf16 MFMA (16x16x32), fp32 accum.

#define B_ 4
#define T_ 2048
#define C_ 1024
#define H_ 16
#define BT_ 8192

typedef __attribute__((ext_vector_type(8))) __bf16 bf16x8;
typedef __attribute__((ext_vector_type(4))) __bf16 bf16x4;
typedef __attribute__((ext_vector_type(4))) float f32x4;

#define WAIT_LGKM0 asm volatile("s_waitcnt lgkmcnt(0)" ::: "memory")
#define WAIT_VM(N) asm volatile("s_waitcnt vmcnt(" #N ")" ::: "memory")

__device__ __forceinline__ void gload_lds16(const void* g, void* l) {
  __builtin_amdgcn_global_load_lds((const __attribute__((address_space(1))) void*)g,
                                   (__attribute__((address_space(3))) void*)l, 16, 0, 0);
}

__device__ __forceinline__ void block_sync() {
  asm volatile("" ::: "memory");
  __builtin_amdgcn_s_barrier();
  asm volatile("" ::: "memory");
}

// ---------------- transpose fp32 [R][Cc] -> bf16 [Cc][R], batched ----------------
__global__ __launch_bounds__(256) void transpose_f32_bf16(
    const float* __restrict__ in, __bf16* __restrict__ out,
    int R, int Cc, long inBatch, long outBatch) {
  __shared__ float tile[32][33];
  const int tx = threadIdx.x, ty = threadIdx.y;
  in += (long)blockIdx.z * inBatch;
  out += (long)blockIdx.z * outBatch;
  const int r0 = blockIdx.y * 32, c0 = blockIdx.x * 32;
#pragma unroll
  for (int i = 0; i < 4; i++)
    tile[ty + i * 8][tx] = in[(long)(r0 + ty + i * 8) * Cc + c0 + tx];
  __syncthreads();
#pragma unroll
  for (int i = 0; i < 4; i++)
    out[(long)(c0 + ty + i * 8) * R + r0 + tx] = (__bf16)tile[tx][ty + i * 8];
}

// ---------------- LayerNorm: fp32 [rows][1024] -> bf16 ----------------
__global__ __launch_bounds__(256) void ln_fwd(const float* __restrict__ x,
                                              const float* __restrict__ g,
                                              const float* __restrict__ bta,
                                              __bf16* __restrict__ out) {
  const long row = blockIdx.x;
  const int tid = threadIdx.x;
  float4 v = ((const float4*)(x + row * C_))[tid];
  float vals[4] = {v.x, v.y, v.z, v.w};
  float s = vals[0] + vals[1] + vals[2] + vals[3];
  float s2 = vals[0] * vals[0] + vals[1] * vals[1] + vals[2] * vals[2] + vals[3] * vals[3];
#pragma unroll
  for (int o = 1; o < 64; o <<= 1) {
    s += __shfl_xor(s, o);
    s2 += __shfl_xor(s2, o);
  }
  __shared__ float red[8];
  const int lane = tid & 63, wid = tid >> 6;
  if (lane == 0) { red[wid] = s; red[wid + 4] = s2; }
  __syncthreads();
  const float S = red[0] + red[1] + red[2] + red[3];
  const float S2 = red[4] + red[5] + red[6] + red[7];
  const float mu = S * (1.0f / C_);
  const float var = S2 * (1.0f / C_) - mu * mu;
  const float rs = rsqrtf(var + 1e-5f);
  bf16x4 o4;
#pragma unroll
  for (int j = 0; j < 4; j++) {
    const int c = tid * 4 + j;
    o4[j] = (__bf16)((vals[j] - mu) * rs * g[c] + bta[c]);
  }
  *(bf16x4*)(out + row * C_ + tid * 4) = o4;
}

// ---------------- GEMM 8-phase: 128x256 tile, BK=64, deep-pipelined ----------------
// A[M,K] x Bt[N,K]. 512 thr = 8 waves (2M x 4N), per-wave 64x64 (4rf x 4cf).
// LDS 96KB: A[2buf][2kh][128x32] + B[2buf][2kh][256x32].
// Per phase: 8 ds_read_b128; stage 3 gload_lds (slots freed at prev closing barrier,
// tile cur+2); counted vmcnt(6); mid-barrier; lgkmcnt0; 16 MFMA (setprio); closing barrier.
// Chunk swizzle pos^=((row>>1)&3) on both stage-source and ds_read (0 conflicts measured).
// EPI 0: bf16 bias+relu. EPI 1: QKV routing (V transposed). EPI 2: fp32 bias+resid.
template <int EPI>
__global__ __launch_bounds__(512, 2) void gemm8p(
    const __bf16* __restrict__ A, const __bf16* __restrict__ Bt,
    void* out0, void* out1, void* out2,
    const float* __restrict__ bias, const float* __restrict__ resid,
    int M, int N, int K, int nwg) {
  __shared__ __bf16 sm[49152];
  __bf16* ldsA = &sm[0];
  __bf16* ldsB = &sm[16384];
  const int tid = threadIdx.x, lane = tid & 63, wid = tid >> 6;
  const int wm = wid >> 2, wn = wid & 3;
  const int l15 = lane & 15, qtr = lane >> 4;
  // bijective chunked XCD swizzle (nwg % 8 == 0); m-fast decode => XCD shares B-panel
  const int q8 = nwg >> 3;
  const int wg = (blockIdx.x & 7) * q8 + (blockIdx.x >> 3);
  const int mBlocks = M >> 7;
  const long mBase = (long)(wg % mBlocks) * 128;
  const long nBase = (long)(wg / mBlocks) * 256;
  const int NT = K >> 6;

  f32x4 acc[4][4] = {};

  // staging source (pre-swizzled global chunk): row = tid>>2, pos = tid&3
  const int spos = (tid & 3) ^ ((tid >> 3) & 3);
  const __bf16* aS = A + (mBase + (tid >> 2)) * (long)K + spos * 8;
  const __bf16* bS0 = Bt + (nBase + (tid >> 2)) * (long)K + spos * 8;
  const __bf16* bS1 = bS0 + 128 * (long)K;

  // fragment-read offsets
  const int posRd = (qtr ^ ((l15 >> 1) & 3)) * 8;
  const int aRd = (wm * 64 + l15) * 32 + posRd;
  const int bRd = (wn * 64 + l15) * 32 + posRd;

#define STG_A(BUF, KT, KH) gload_lds16(aS + (KT) * 64 + (KH) * 32, ldsA + (BUF) * 8192 + (KH) * 4096 + tid * 8)
#define STG_B(BUF, KT, KH)                                                                    \
  do {                                                                                        \
    gload_lds16(bS0 + (KT) * 64 + (KH) * 32, ldsB + (BUF) * 16384 + (KH) * 8192 + tid * 8);   \
    gload_lds16(bS1 + (KT) * 64 + (KH) * 32, ldsB + (BUF) * 16384 + (KH) * 8192 + 4096 + tid * 8); \
  } while (0)

#define GPHASE(BUF, KH, VMN, ...)                                                          \
  do {                                                                                     \
    bf16x8 af0 = *(const bf16x8*)&ldsA[(BUF) * 8192 + (KH) * 4096 + aRd];                  \
    bf16x8 af1 = *(const bf16x8*)&ldsA[(BUF) * 8192 + (KH) * 4096 + aRd + 512];            \
    bf16x8 af2 = *(const bf16x8*)&ldsA[(BUF) * 8192 + (KH) * 4096 + aRd + 1024];           \
    bf16x8 af3 = *(const bf16x8*)&ldsA[(BUF) * 8192 + (KH) * 4096 + aRd + 1536];           \
    bf16x8 bf0 = *(const bf16x8*)&ldsB[(BUF) * 16384 + (KH) * 8192 + bRd];                 \
    bf16x8 bf1 = *(const bf16x8*)&ldsB[(BUF) * 16384 + (KH) * 8192 + bRd + 512];           \
    bf16x8 bf2 = *(const bf16x8*)&ldsB[(BUF) * 16384 + (KH) * 8192 + bRd + 1024];          \
    bf16x8 bf3 = *(const bf16x8*)&ldsB[(BUF) * 16384 + (KH) * 8192 + bRd + 1536];          \
    __VA_ARGS__;                                                                           \
    WAIT_VM(VMN);                                                                          \
    block_sync();                                                                          \
    WAIT_LGKM0;                                                                            \
    __builtin_amdgcn_sched_barrier(0);                                                     \
    __builtin_amdgcn_s_setprio(1);                                                         \
    acc[0][0] = __builtin_amdgcn_mfma_f32_16x16x32_bf16(af0, bf0, acc[0][0], 0, 0, 0);     \
    acc[0][1] = __builtin_amdgcn_mfma_f32_16x16x32_bf16(af0, bf1, acc[0][1], 0, 0, 0);     \
    acc[0][2] = __builtin_amdgcn_mfma_f32_16x16x32_bf16(af0, bf2, acc[0][2], 0, 0, 0);     \
    acc[0][3] = __builtin_amdgcn_mfma_f32_16x16x32_bf16(af0, bf3, acc[0][3], 0, 0, 0);     \
    acc[1][0] = __builtin_amdgcn_mfma_f32_16x16x32_bf16(af1, bf0, acc[1][0], 0, 0, 0);     \
    acc[1][1] = __builtin_amdgcn_mfma_f32_16x16x32_bf16(af1, bf1, acc[1][1], 0, 0, 0);     \
    acc[1][2] = __builtin_amdgcn_mfma_f32_16x16x32_bf16(af1, bf2, acc[1][2], 0, 0, 0);     \
    acc[1][3] = __builtin_amdgcn_mfma_f32_16x16x32_bf16(af1, bf3, acc[1][3], 0, 0, 0);     \
    acc[2][0] = __builtin_amdgcn_mfma_f32_16x16x32_bf16(af2, bf0, acc[2][0], 0, 0, 0);     \
    acc[2][1] = __builtin_amdgcn_mfma_f32_16x16x32_bf16(af2, bf1, acc[2][1], 0, 0, 0);     \
    acc[2][2] = __builtin_amdgcn_mfma_f32_16x16x32_bf16(af2, bf2, acc[2][2], 0, 0, 0);     \
    acc[2][3] = __builtin_amdgcn_mfma_f32_16x16x32_bf16(af2, bf3, acc[2][3], 0, 0, 0);     \
    acc[3][0] = __builtin_amdgcn_mfma_f32_16x16x32_bf16(af3, bf0, acc[3][0], 0, 0, 0);     \
    acc[3][1] = __builtin_amdgcn_mfma_f32_16x16x32_bf16(af3, bf1, acc[3][1], 0, 0, 0);     \
    acc[3][2] = __builtin_amdgcn_mfma_f32_16x16x32_bf16(af3, bf2, acc[3][2], 0, 0, 0);     \
    acc[3][3] = __builtin_amdgcn_mfma_f32_16x16x32_bf16(af3, bf3, acc[3][3], 0, 0, 0);     \
    __builtin_amdgcn_s_setprio(0);                                                         \
    block_sync();                                                                          \
  } while (0)

  // prologue: k0(0), k1(0), k0(1) = 9 loads; wait for k0(0)
  STG_A(0, 0, 0); STG_B(0, 0, 0);
  STG_A(0, 0, 1); STG_B(0, 0, 1);
  STG_A(1, 1, 0); STG_B(1, 1, 0);
  WAIT_VM(6);
  block_sync();

  // main: tiles (T, T+1), T = 0,2,..,NT-4
  for (int T = 0; T + 3 < NT; T += 2) {
    GPHASE(0, 0, 6, STG_A(1, T + 1, 1); STG_B(1, T + 1, 1));
    GPHASE(0, 1, 6, STG_A(0, T + 2, 0); STG_B(0, T + 2, 0));
    GPHASE(1, 0, 6, STG_A(0, T + 2, 1); STG_B(0, T + 2, 1));
    GPHASE(1, 1, 6, STG_A(1, T + 3, 0); STG_B(1, T + 3, 0));
  }
  // tail: tiles NT-2 (buf0), NT-1 (buf1)
  GPHASE(0, 0, 6, STG_A(1, NT - 1, 1); STG_B(1, NT - 1, 1));
  GPHASE(0, 1, 3, );
  GPHASE(1, 0, 0, );
  GPHASE(1, 1, 0, );

#undef GPHASE
#undef STG_A
#undef STG_B

  // ---- epilogue
  if (EPI == 0) {
    __bf16* outB = (__bf16*)out0;
#pragma unroll
    for (int cf = 0; cf < 4; cf++) {
      const long gc = nBase + wn * 64 + cf * 16 + l15;
      const float bv = bias[gc];
#pragma unroll
      for (int rf = 0; rf < 4; rf++) {
        const long gr0 = mBase + wm * 64 + rf * 16 + qtr * 4;
#pragma unroll
        for (int r = 0; r < 4; r++)
          outB[(gr0 + r) * (long)N + gc] = (__bf16)fmaxf(acc[rf][cf][r] + bv, 0.0f);
      }
    }
  } else if (EPI == 2) {
    float* outF = (float*)out0;
#pragma unroll
    for (int cf = 0; cf < 4; cf++) {
      const long gc = nBase + wn * 64 + cf * 16 + l15;
      const float bv = bias[gc];
#pragma unroll
      for (int rf = 0; rf < 4; rf++) {
        const long gr0 = mBase + wm * 64 + rf * 16 + qtr * 4;
#pragma unroll
        for (int r = 0; r < 4; r++)
          outF[(gr0 + r) * (long)N + gc] = acc[rf][cf][r] + bv + resid[(gr0 + r) * (long)N + gc];
      }
    }
  } else {
    // QKV routing: seg 0 -> Q [BT,1024], 1 -> K [BT,1024], 2 -> V transposed [1024][BT]
    const int seg = (int)(nBase >> 10);
#pragma unroll
    for (int cf = 0; cf < 4; cf++) {
      const long gc = nBase + wn * 64 + cf * 16 + l15;
      const long cc = gc & 1023;
#pragma unroll
      for (int rf = 0; rf < 4; rf++) {
        const long gr0 = mBase + wm * 64 + rf * 16 + qtr * 4;
        if (seg == 0) {
          __bf16* Qb = (__bf16*)out0;
#pragma unroll
          for (int r = 0; r < 4; r++) Qb[(gr0 + r) * 1024 + cc] = (__bf16)acc[rf][cf][r];
        } else if (seg == 1) {
          __bf16* Kb = (__bf16*)out1;
#pragma unroll
          for (int r = 0; r < 4; r++) Kb[(gr0 + r) * 1024 + cc] = (__bf16)acc[rf][cf][r];
        } else {
          __bf16* Vtg = (__bf16*)out2;
          bf16x4 v4;
#pragma unroll
          for (int r = 0; r < 4; r++) v4[r] = (__bf16)acc[rf][cf][r];
          *(bf16x4*)&Vtg[cc * (long)BT_ + gr0] = v4;
        }
      }
    }
  }
}

// ---------------- causal flash attention v2 ----------------
// grid (B*H, 16): blockIdx.x = bh so all q-blocks of a head share an XCD (wgid%8).
// log2-domain softmax (Q pre-scaled by 0.125*log2e); defer-max (T13, THR=8).
// P spill packed: 4x ds_write_b64 per tile (was 16x ds_write_u16).
#define PSTR 72
__global__ __launch_bounds__(512, 6) void attn_fwd2(
    const __bf16* __restrict__ Qg, const __bf16* __restrict__ Kg,
    const __bf16* __restrict__ Vtg, __bf16* __restrict__ O) {
  __shared__ __bf16 Ks[2][64 * 64];
  __shared__ __bf16 Vs[2][64 * 64];
  __shared__ __bf16 Ps[128 * PSTR];
  const int tid = threadIdx.x, lane = tid & 63, wid = tid >> 6;
  const int bh = blockIdx.x, b = bh >> 4, h = bh & 15;
  const int qx = 15 - blockIdx.y;           // heavy blocks first
  const int qBase = qx * 128;
  const int qw = qBase + wid * 16;
  const int qwTop = qw + 15;
  const long bT = (long)b * T_;
  const int l15 = lane & 15, qtr = lane >> 4;
  const int q_lane = qw + l15;

  const int srow = tid >> 3;
  const int schunk = (tid & 7) ^ (srow & 7);
  const __bf16* kSrcBase = Kg + (bT + srow) * C_ + h * 64 + schunk * 8;
  const __bf16* vSrcBase = Vtg + (long)(h * 64 + srow) * BT_ + bT + schunk * 8;
  __bf16* kDst = &Ks[0][tid * 8];
  __bf16* vDst = &Vs[0][tid * 8];
  const int bufStride = 64 * 64;

  // hoisted P-spill bases (write: lane owns q=l15 row, cols qtr*4 + kb*16;
  // read: A-frag row l15, chunk s*32+qtr*8)
  __bf16* psW = &Ps[(wid * 16 + l15) * PSTR + qtr * 4];
  const __bf16* psR = &Ps[(wid * 16 + l15) * PSTR + qtr * 8];

  bf16x8 q0s, q1s;
  {
    const float SC = 0.125f * 1.44269504089f;  // 1/sqrt(64) * log2(e)
    bf16x8 r0 = *(const bf16x8*)(Qg + (bT + q_lane) * C_ + h * 64 + qtr * 8);
    bf16x8 r1 = *(const bf16x8*)(Qg + (bT + q_lane) * C_ + h * 64 + 32 + qtr * 8);
#pragma unroll
    for (int j = 0; j < 8; j++) {
      q0s[j] = (__bf16)((float)r0[j] * SC);
      q1s[j] = (__bf16)((float)r1[j] * SC);
    }
  }

  f32x4 o[4] = {};
  float m_ = -1e30f, l_ = 0.0f;
  const int nkt = 2 * qx + 2;

  gload_lds16(kSrcBase, kDst);
  gload_lds16(vSrcBase, vDst);
  __syncthreads();

  int buf = 0;
  for (int t = 0; t < nkt; t++) {
    const int k0 = t * 64;
    if (t + 1 < nkt) {
      const long koff = (long)(k0 + 64);
      gload_lds16(kSrcBase + koff * C_, kDst + (buf ^ 1) * bufStride);
      gload_lds16(vSrcBase + koff, vDst + (buf ^ 1) * bufStride);
    }
    if (k0 <= qwTop) {
      const __bf16* ks = Ks[buf];
      const __bf16* vs = Vs[buf];
      f32x4 sT[4] = {};
      __builtin_amdgcn_s_setprio(1);
#pragma unroll
      for (int kb = 0; kb < 4; kb++) {
        bf16x8 aK0 = *(const bf16x8*)&ks[(kb * 16 + l15) * 64 + ((qtr ^ (l15 & 7)) * 8)];
        bf16x8 aK1 = *(const bf16x8*)&ks[(kb * 16 + l15) * 64 + (((4 + qtr) ^ (l15 & 7)) * 8)];
        sT[kb] = __builtin_amdgcn_mfma_f32_16x16x32_bf16(aK0, q0s, sT[kb], 0, 0, 0);
        sT[kb] = __builtin_amdgcn_mfma_f32_16x16x32_bf16(aK1, q1s, sT[kb], 0, 0, 0);
      }
      __builtin_amdgcn_s_setprio(0);
      if (k0 + 63 > qw) {
#pragma unroll
        for (int kb = 0; kb < 4; kb++)
#pragma unroll
          for (int r = 0; r < 4; r++)
            if (k0 + kb * 16 + qtr * 4 + r > q_lane) sT[kb][r] = -1e30f;
      }
      float mx = -1e30f;
#pragma unroll
      for (int kb = 0; kb < 4; kb++)
#pragma unroll
        for (int r = 0; r < 4; r++) mx = fmaxf(mx, sT[kb][r]);
      mx = fmaxf(mx, __shfl_xor(mx, 16));
      mx = fmaxf(mx, __shfl_xor(mx, 32));
      // defer-max: skip rescale when no row grew by > 8 (log2 units; P <= 256)
      const bool defer = __all(mx - m_ <= 8.0f);
      const float mnew = defer ? m_ : fmaxf(m_, mx);
      float psum = 0.0f;
#pragma unroll
      for (int kb = 0; kb < 4; kb++) {
        bf16x4 p4;
#pragma unroll
        for (int r = 0; r < 4; r++) {
          const float pv = exp2f(sT[kb][r] - mnew);
          psum += pv;
          p4[r] = (__bf16)pv;
        }
        *(bf16x4*)&psW[kb * 16] = p4;  // one ds_write_b64 per kb
      }
      psum += __shfl_xor(psum, 16);
      psum += __shfl_xor(psum, 32);
      if (defer) {
        l_ += psum;
      } else {
        const float fac = exp2f(m_ - mnew);
        l_ = l_ * fac + psum;
        m_ = mnew;
#pragma unroll
        for (int r = 0; r < 4; r++) {
          const float fr = __shfl(fac, (lane & 48) + qtr * 4 + r);
#pragma unroll
          for (int dg = 0; dg < 4; dg++) o[dg][r] *= fr;
        }
      }
      __builtin_amdgcn_s_setprio(1);
#pragma unroll
      for (int s = 0; s < 2; s++) {
        bf16x8 aP = *(const bf16x8*)&psR[s * 32];
#pragma unroll
        for (int dg = 0; dg < 4; dg++) {
          bf16x8 bV = *(const bf16x8*)&vs[(dg * 16 + l15) * 64 + (((s * 4 + qtr) ^ (l15 & 7)) * 8)];
          o[dg] = __builtin_amdgcn_mfma_f32_16x16x32_bf16(aP, bV, o[dg], 0, 0, 0);
        }
      }
      __builtin_amdgcn_s_setprio(0);
    }
    __syncthreads();
    buf ^= 1;
  }

  const float linv = 1.0f / l_;
#pragma unroll
  for (int r = 0; r < 4; r++) {
    const float lr = __shfl(linv, (lane & 48) + qtr * 4 + r);
    const long row = bT + qw + qtr * 4 + r;
#pragma unroll
    for (int dg = 0; dg < 4; dg++)
      O[row * C_ + h * 64 + dg * 16 + l15] = (__bf16)(o[dg][r] * lr);
  }
}

// ---------------- launch ----------------
extern "C" void kernel_launch(void* const* d_in, const int* in_sizes, int n_in,
                              void* d_out, int out_size, void* d_ws, size_t ws_size,
                              hipStream_t stream) {
  const float* x = (const float*)d_in[0];
  const float* wq = (const float*)d_in[1];
  const float* wk = (const float*)d_in[2];
  const float* wv = (const float*)d_in[3];
  const float* wproj = (const float*)d_in[4];
  const float* bproj = (const float*)d_in[5];
  const float* w1 = (const float*)d_in[6];
  const float* b1 = (const float*)d_in[7];
  const float* w2 = (const float*)d_in[8];
  const float* b2 = (const float*)d_in[9];
  const float* g1 = (const float*)d_in[10];
  const float* be1 = (const float*)d_in[11];
  const float* g2 = (const float*)d_in[12];
  const float* be2 = (const float*)d_in[13];

  char* ws = (char*)d_ws;
  const size_t MB = 1024ull * 1024ull;
  __bf16* h1 = (__bf16*)(ws + 0);          // 16MB; reused as att after QKV
  __bf16* Qb = (__bf16*)(ws + 16 * MB);    // 16MB; reused as h2 after attn
  __bf16* Kb = (__bf16*)(ws + 32 * MB);    // 16MB
  __bf16* Vtg = (__bf16*)(ws + 48 * MB);   // 16MB, V pre-transposed [C][B*T]
  __bf16* ff1 = (__bf16*)(ws + 32 * MB);   // 64MB, aliases Kb/Vtg (dead after attn)
  __bf16* wqt = (__bf16*)(ws + 96 * MB);   // wqt/wkt/wvt contiguous => [3072][1024]
  __bf16* wkt = (__bf16*)(ws + 98 * MB);
  __bf16* wvt = (__bf16*)(ws + 100 * MB);
  __bf16* wpt = (__bf16*)(ws + 102 * MB);
  __bf16* w1t = (__bf16*)(ws + 104 * MB);  // 8MB
  __bf16* w2t = (__bf16*)(ws + 112 * MB);  // 8MB
  __bf16* att = h1;
  __bf16* h2 = Qb;
  float* xout = (float*)d_out;

  dim3 tb(32, 8);
  transpose_f32_bf16<<<dim3(2, 32, 16), tb, 0, stream>>>(wq, wqt, 1024, 64, 1024 * 64, 64 * 1024);
  transpose_f32_bf16<<<dim3(2, 32, 16), tb, 0, stream>>>(wk, wkt, 1024, 64, 1024 * 64, 64 * 1024);
  transpose_f32_bf16<<<dim3(2, 32, 16), tb, 0, stream>>>(wv, wvt, 1024, 64, 1024 * 64, 64 * 1024);
  transpose_f32_bf16<<<dim3(32, 32, 1), tb, 0, stream>>>(wproj, wpt, 1024, 1024, 0, 0);
  transpose_f32_bf16<<<dim3(128, 32, 1), tb, 0, stream>>>(w1, w1t, 1024, 4096, 0, 0);
  transpose_f32_bf16<<<dim3(32, 128, 1), tb, 0, stream>>>(w2, w2t, 4096, 1024, 0, 0);

  ln_fwd<<<8192, 256, 0, stream>>>(x, g1, be1, h1);
  // fused QKV: Bt = [wqt|wkt|wvt] = [3072][1024]; 64 m-blocks x 12 n-blocks
  gemm8p<1><<<768, 512, 0, stream>>>(h1, wqt, Qb, Kb, Vtg, nullptr, nullptr, 8192, 3072, 1024, 768);
  attn_fwd2<<<dim3(64, 16), 512, 0, stream>>>(Qb, Kb, Vtg, att);
  gemm8p<2><<<256, 512, 0, stream>>>(att, wpt, xout, nullptr, nullptr, bproj, x, 8192, 1024, 1024, 256);
  ln_fwd<<<8192, 256, 0, stream>>>(xout, g2, be2, h2);
  gemm8p<0><<<1024, 512, 0, stream>>>(h2, w1t, ff1, nullptr, nullptr, b1, nullptr, 8192, 4096, 1024, 1024);
  gemm8p<2><<<256, 512, 0, stream>>>(ff1, w2t, xout, nullptr, nullptr, b2, (const float*)xout, 8192, 1024, 4096, 256);
}